// Round 5
// baseline (113.401 us; speedup 1.0000x reference)
//
#include <hip/hip_runtime.h>

// Problem constants
#define B_SIZE 16384
#define D_DIM  1024
#define T_DIM  128
#define VLn    12
#define BM     64              // rows per block
#define BKF    64              // K floats per chunk
#define NCHUNK 16              // 1024 / 64
#define NTHR   512             // 8 waves
#define GRID   (B_SIZE / BM)   // 256 blocks = exactly 1 per CU
#define AROWB  264             // A row stride in LDS: 256 B + 8 pad (bank spread)
#define ACHB   (BM * AROWB)    // 16896 B A-chunk
#define BCHB   16384           // B-chunk: 128 cols x 64 k x 2 B (contig slice of Wf)
#define PAIRB  (ACHB + BCHB)   // 33280 B per ring slot
#define SLSTR  132

typedef _Float16 half8  __attribute__((ext_vector_type(8)));
typedef __fp16   fp16x2 __attribute__((ext_vector_type(2)));
typedef float    f32x4  __attribute__((ext_vector_type(4)));

union Pack16 { fp16x2 h[4]; uint4 u; half8 v; };
union Frag   { uint4 u; half8 h; };

__device__ __forceinline__ uint4 pack8u(float4 v0, float4 v1) {
    Pack16 un;
    un.h[0] = __builtin_amdgcn_cvt_pkrtz(v0.x, v0.y);
    un.h[1] = __builtin_amdgcn_cvt_pkrtz(v0.z, v0.w);
    un.h[2] = __builtin_amdgcn_cvt_pkrtz(v1.x, v1.y);
    un.h[3] = __builtin_amdgcn_cvt_pkrtz(v1.z, v1.w);
    return un.u;
}
// build f16 A-frag from 8 consecutive f32 in LDS (8-B aligned)
__device__ __forceinline__ half8 pack8f(const float* fp) {
    const float2 a = ((const float2*)fp)[0];
    const float2 b = ((const float2*)fp)[1];
    const float2 c = ((const float2*)fp)[2];
    const float2 d = ((const float2*)fp)[3];
    Pack16 un;
    un.h[0] = __builtin_amdgcn_cvt_pkrtz(a.x, a.y);
    un.h[1] = __builtin_amdgcn_cvt_pkrtz(b.x, b.y);
    un.h[2] = __builtin_amdgcn_cvt_pkrtz(c.x, c.y);
    un.h[3] = __builtin_amdgcn_cvt_pkrtz(d.x, d.y);
    return un.v;
}

// async global->LDS DMA; LDS dest = wave-uniform base + lane*size
__device__ __forceinline__ void dma16(const uint4* g, void* l) {
    __builtin_amdgcn_global_load_lds(
        (const __attribute__((address_space(1))) void*)g,
        (__attribute__((address_space(3))) void*)l, 16, 0, 0);
}
__device__ __forceinline__ void dma4(const float* g, void* l) {
    __builtin_amdgcn_global_load_lds(
        (const __attribute__((address_space(1))) void*)g,
        (__attribute__((address_space(3))) void*)l, 4, 0, 0);
}

#define WAITV(n) asm volatile("s_waitcnt vmcnt(" #n ")" ::: "memory")
#define SB0()    __builtin_amdgcn_sched_barrier(0)

// W fp32 [128][1024] -> f16, swizzled into MFMA B-fragment order (verified):
// unit j: kcW=j>>10, g=(j&1023)>>6, lane=j&63;
// holds W[n = (g&7)*16 + (lane&15)][k = kcW*64 + (g>>3)*32 + (lane>>4)*8 .. +8].
// Also zeroes the scalar output (replaces the hipMemsetAsync dispatch).
__global__ __launch_bounds__(256)
void conv_w(const float* __restrict__ W, uint4* __restrict__ Wf,
            float* __restrict__ out) {
    if (blockIdx.x == 0 && threadIdx.x == 0) out[0] = 0.0f;
    const int j    = blockIdx.x * 256 + threadIdx.x;   // 0..16383
    const int kc   = j >> 10;
    const int r    = j & 1023;
    const int g    = r >> 6;
    const int lane = r & 63;
    const int n = (g & 7) * 16 + (lane & 15);
    const int k = kc * 64 + (g >> 3) * 32 + ((lane >> 4) << 3);
    const float* src = W + (size_t)n * D_DIM + k;
    Wf[j] = pack8u(*(const float4*)src, *(const float4*)(src + 4));
}

// 256 blocks x 512 threads (8 waves) = exactly 1 block/CU, all concurrent.
// Block = 64 rows x 128 cols x full K.
// KEY CHANGE vs the ~112-us versions: B (Wf) is now STAGED IN LDS per chunk
// and shared by all 8 waves, instead of each wave redundantly loading its own
// B frags from L2. Per-block VMEM drops 640 KB -> 512 KB while covering 2x
// the rows: total TCP/L2 ingest 328 MB -> 128 MB. The dominant remaining
// stream is the A read (64 MB from HBM/L3) => memory-roofline-bound design.
//   Ring: 4 buffers x (A 16.9 KB + B 16 KB) = 130 KB LDS; DMA issued 3
//   chunks ahead (~>=1000 cyc of cover). Per chunk per wave: 8 width-4 A-row
//   DMAs + 2 width-16 B DMAs = 10 calls.
//   Chunk protocol: WAITV(20) (retire own chunk-kc DMAs; 2 newer chunks stay
//   in flight) -> s_barrier (also guarantees all waves finished reading the
//   buffer DMA(kc+3) will overwrite) -> issue DMA(kc+3) -> compute(kc).
//   vmcnt never drains to 0 in the main loop.
// Compute: wave w owns rows 16*(w&3)..+15 and col-tiles 4*(w>>2)..+3.
//   A frags: ds_read_b64 x4 from padded rows (264-B stride -> bank-spread);
//   B frags: ds_read_b128, 64 lanes x consecutive 16 B -> conflict-free.
__global__ __launch_bounds__(NTHR, 2)
void qloss_kernel(const float* __restrict__ emb,
                  const uint4* __restrict__ Wf,
                  const float* __restrict__ bias,
                  const int*   __restrict__ didx,
                  const int*   __restrict__ dmsk,
                  float*       __restrict__ out)
{
    __shared__ __align__(16) unsigned char smem[4 * PAIRB + 64];   // 133184 B
    float* sL   = (float*)smem;                    // [64][132] epilogue alias
    float* sRed = (float*)(smem + 4 * PAIRB);

    const int t    = threadIdx.x;
    const int w    = t >> 6;
    const int lane = t & 63;
    const int m15  = lane & 15;
    const int quad = lane >> 4;
    const int r0   = blockIdx.x * BM;

    const int rr = w & 3;        // row-group: rows 16rr..16rr+15
    const int cg = w >> 2;       // col-group: col-tiles 4cg..4cg+3

    // DMA sources (global side is per-lane; LDS side is uniform base + lane*sz)
    const float* aS = emb + (size_t)(r0 + 8 * w) * D_DIM + lane;   // +lane*4 B
    const uint4* bS = Wf + 2 * w * 64 + lane;                      // +lane*16 B

    f32x4 acc[4];
#pragma unroll
    for (int ct = 0; ct < 4; ++ct) acc[ct] = (f32x4){0.f, 0.f, 0.f, 0.f};

    // issue all 10 DMA calls for chunk j into ring slot j&3
    auto issue = [&](int j) {
        unsigned char* Ab = smem + (j & 3) * PAIRB;
#pragma unroll
        for (int r = 0; r < 8; ++r)
            dma4(aS + (size_t)r * D_DIM + j * BKF, Ab + (8 * w + r) * AROWB);
        unsigned char* Bb = Ab + ACHB;
        dma16(bS + (size_t)j * 1024,      Bb + (2 * w) * 1024);
        dma16(bS + (size_t)j * 1024 + 64, Bb + (2 * w + 1) * 1024);
    };

    // compute chunk kc from ring slot kc&3 (2 k-steps x 4 col-tiles)
    auto compute = [&](int kc) {
        const unsigned char* pb = smem + (kc & 3) * PAIRB;
        const float* Af = (const float*)pb;
        const uint4* Bf = (const uint4*)(pb + ACHB);
#pragma unroll
        for (int st = 0; st < 2; ++st) {
            const float* fp = Af + (16 * rr + m15) * (AROWB / 4) + st * 32 + quad * 8;
            const half8 a = pack8f(fp);
#pragma unroll
            for (int ct = 0; ct < 4; ++ct) {
                Frag b;
                b.u = Bf[(st * 8 + 4 * cg + ct) * 64 + lane];
                acc[ct] = __builtin_amdgcn_mfma_f32_16x16x32_f16(a, b.h, acc[ct], 0, 0, 0);
            }
        }
    };

    // ---- prologue: 3 chunks in flight ----
    issue(0); issue(1); issue(2);

    // ---- main loop: kc = 0..12, issuing DMA(kc+3) after the barrier ----
#pragma unroll
    for (int kc = 0; kc < NCHUNK - 3; ++kc) {
        // retire own DMA(kc) (10 oldest); chunks kc+1, kc+2 stay in flight
        WAITV(20);
        SB0();
        __builtin_amdgcn_s_barrier();   // all waves: DMA(kc) done everywhere,
        SB0();                          // and all reads of slot (kc+3)&3 done
        issue(kc + 3);
        SB0();
        compute(kc);
    }
    // ---- tail chunks 13, 14, 15 (no more issues; counts shrink) ----
    WAITV(20); SB0(); __builtin_amdgcn_s_barrier(); SB0(); compute(13);
    WAITV(10); SB0(); __builtin_amdgcn_s_barrier(); SB0(); compute(14);
    WAITV(0);  SB0(); __builtin_amdgcn_s_barrier(); SB0(); compute(15);

    // ---- epilogue: logits -> sL (aliases ring slots 0/1; all reads done) ----
    __syncthreads();
    float bv[4];
#pragma unroll
    for (int ct = 0; ct < 4; ++ct) bv[ct] = bias[(4 * cg + ct) * 16 + m15];
#pragma unroll
    for (int i = 0; i < 4; ++i) {
        const int row = 16 * rr + quad * 4 + i;
#pragma unroll
        for (int ct = 0; ct < 4; ++ct)
            sL[row * SLSTR + (4 * cg + ct) * 16 + m15] = acc[ct][i] + bv[ct];
    }
    __syncthreads();

    // softmax: 512 threads = 64 rows x 8 threads, 16 cols each
    {
        const int row = t >> 3, sub = t & 7;
        float* base = &sL[row * SLSTR + sub * 16];
        float v[16];
        *(float4*)&v[0]  = *(const float4*)(base);
        *(float4*)&v[4]  = *(const float4*)(base + 4);
        *(float4*)&v[8]  = *(const float4*)(base + 8);
        *(float4*)&v[12] = *(const float4*)(base + 12);
        float m = -1e30f;
#pragma unroll
        for (int j = 0; j < 16; ++j) m = fmaxf(m, v[j]);
#pragma unroll
        for (int off = 1; off < 8; off <<= 1) m = fmaxf(m, __shfl_xor(m, off));
        float ssum = 0.f;
#pragma unroll
        for (int j = 0; j < 16; ++j) { v[j] = __expf(v[j] - m); ssum += v[j]; }
#pragma unroll
        for (int off = 1; off < 8; off <<= 1) ssum += __shfl_xor(ssum, off);
        const float inv = 1.0f / ssum;
#pragma unroll
        for (int j = 0; j < 16; ++j) v[j] *= inv;
        *(float4*)(base)      = *(const float4*)&v[0];
        *(float4*)(base + 4)  = *(const float4*)&v[4];
        *(float4*)(base + 8)  = *(const float4*)&v[8];
        *(float4*)(base + 12) = *(const float4*)&v[12];
    }
    __syncthreads();

    // gather: 64 rows x 12 labels = 768 items (threads t and 512+t)
    float p = 0.f;
#pragma unroll
    for (int e = 0; e < 2; ++e) {
        const int item = e * 512 + t;
        if (item < BM * VLn) {
            const int gi  = r0 * VLn + item;
            const int row = item / VLn;
            const int mk  = dmsk[gi];
            const int idx = didx[gi];
            if (mk) p += sL[row * SLSTR + idx];
        }
    }
#pragma unroll
    for (int off = 1; off < 64; off <<= 1) p += __shfl_xor(p, off);
    if (lane == 0) sRed[w] = p;
    __syncthreads();
    if (t == 0) {
        float s = 0.f;
#pragma unroll
        for (int i = 0; i < 8; ++i) s += sRed[i];
        atomicAdd(out, s * (1.0f / 65536.0f));
    }
}

extern "C" void kernel_launch(void* const* d_in, const int* in_sizes, int n_in,
                              void* d_out, int out_size, void* d_ws, size_t ws_size,
                              hipStream_t stream) {
    const float* emb  = (const float*)d_in[0];
    const float* W    = (const float*)d_in[1];
    const float* bias = (const float*)d_in[2];
    const int*   didx = (const int*)d_in[3];
    const int*   dmsk = (const int*)d_in[4];
    float* out = (float*)d_out;

    uint4* Wf = (uint4*)d_ws;   // 256 KB swizzled f16 W

    conv_w<<<64, 256, 0, stream>>>(W, Wf, out);
    qloss_kernel<<<GRID, NTHR, 0, stream>>>(emb, Wf, bias, didx, dmsk, out);
}